// Round 18
// baseline (806.526 us; speedup 1.0000x reference)
//
#include <hip/hip_runtime.h>
#include <hip/hip_bf16.h>

typedef __attribute__((ext_vector_type(8))) short bfrag;   // 8 bf16 = 4 VGPR
typedef __attribute__((ext_vector_type(4))) float facc;    // 4 f32 acc
typedef __attribute__((ext_vector_type(4))) unsigned int uifrag; // 16B vector

#define DIN   128
#define HDIM  512
#define DOUT  128
#define K1    384
#define N2    1152
#define MB    32      // triples per block (256 thr)

// LDS layout (40KB):
//   union [0, 32768)   : cur 32x768B (gather/GEMM1 in) UNION h 32x1024B (GEMM2 in)
//                        (h written only AFTER both GEMM1 passes + barrier)
//   stg   [32768,40960): 4 waves x 2KB transpose stage
#define STG_BASE 32768

__device__ __forceinline__ facc mfma16(bfrag a, bfrag b, facc c) {
  return __builtin_amdgcn_mfma_f32_16x16x32_bf16(a, b, c, 0, 0, 0);
}

__device__ __forceinline__ unsigned short bfbits(float x) {
  __hip_bfloat16 b = __float2bfloat16(x);
  return __builtin_bit_cast(unsigned short, b);
}

__device__ __forceinline__ float b2f(short u) {
  return __bfloat162float(__builtin_bit_cast(__hip_bfloat16, (unsigned short)u));
}

// issue 4 coalesced 16B loads (one 4KB step-chunk) into buffer B
#define GLOAD4(B, base)                                                              \
  asm volatile("global_load_dwordx4 %0, %1, off"             : "=v"(B[0]) : "v"(base)); \
  asm volatile("global_load_dwordx4 %0, %1, off offset:1024" : "=v"(B[1]) : "v"(base)); \
  asm volatile("global_load_dwordx4 %0, %1, off offset:2048" : "=v"(B[2]) : "v"(base)); \
  asm volatile("global_load_dwordx4 %0, %1, off offset:3072" : "=v"(B[3]) : "v"(base));

// wait until <= N vmem outstanding, with data-dep on the 4 consumed fragment regs
#define BWAITN(B, N) asm volatile("s_waitcnt vmcnt(" #N ")"                          \
    : "+v"(B[0]), "+v"(B[1]), "+v"(B[2]), "+v"(B[3]) :: "memory")

// single 16B load (phaseB run loop)
#define GL1(D, addr) asm volatile("global_load_dwordx4 %0, %1, off" : "=v"(D) : "v"(addr))

// ---------------- pipelined GEMM inner loop: depth-3 B prefetch ----------------
// Needs generous register budget (launch_bounds min-waves <= 2); at a tight cap
// the allocator spills in-flight asm registers (round-9/10 corruption).
template <int NS, int MF, int STRIDE>
__device__ __forceinline__ void pipeGemm(const char* pw, const char* ldsa,
                                         int l15, int lg, facc (&acc)[MF][4]) {
  uifrag B[4][4];
  GLOAD4(B[0], pw);
  GLOAD4(B[1], pw + 4096);
  GLOAD4(B[2], pw + 8192);
  #pragma unroll
  for (int ks = 0; ks < NS; ++ks) {
    uifrag (&cur)[4] = B[ks & 3];
    if (ks + 3 < NS) {
      GLOAD4(B[(ks + 3) & 3], pw + (size_t)(ks + 3) * 4096);
      BWAITN(cur, 12);
    } else if (ks + 2 < NS) {
      BWAITN(cur, 8);
    } else if (ks + 1 < NS) {
      BWAITN(cur, 4);
    } else {
      BWAITN(cur, 0);
    }
    int k0 = ks * 32 + lg * 8;
    bfrag af[MF];
    #pragma unroll
    for (int mf = 0; mf < MF; ++mf) {
      int row = mf * 16 + l15;
      int off = (row * STRIDE + k0 * 2) ^ ((row & 7) << 4);
      af[mf] = *reinterpret_cast<const bfrag*>(ldsa + off);
    }
    #pragma unroll
    for (int mf = 0; mf < MF; ++mf)
      #pragma unroll
      for (int nf = 0; nf < 4; ++nf)
        acc[mf][nf] = mfma16(af[mf], __builtin_bit_cast(bfrag, cur[nf]), acc[mf][nf]);
  }
}

// ---------------- weight transpose + f32->bf16 (per call; tiny) ----------------
__global__ void ktranspose(const float* __restrict__ in,
                           __hip_bfloat16* __restrict__ out, int rows, int cols) {
  int idx = blockIdx.x * 256 + threadIdx.x;
  if (idx < rows * cols) {
    int i = idx / cols;
    int j = idx - i * cols;
    out[(size_t)j * rows + i] = __float2bfloat16(in[idx]);
  }
}

// ---------------- weight pack: [K][N] f32 -> per-(tile64,ks,frag16) 1KB chunks ----
__global__ void kpack(const float* __restrict__ in, __hip_bfloat16* __restrict__ out,
                      int K, int N) {
  int idx = blockIdx.x * 256 + threadIdx.x;
  if (idx >= K * N) return;
  int k = idx / N;
  int n = idx - k * N;
  int ks = k >> 5, lg = (k >> 3) & 3, j = k & 7;
  int w = n >> 6, nf = (n >> 4) & 3, l15 = n & 15;
  int nsteps = K >> 5;
  size_t dst = ((size_t)(w * nsteps + ks) * 4 + nf) * 512 + (lg * 16 + l15) * 8 + j;
  out[dst] = __float2bfloat16(in[idx]);
}

// ---------------- CSR build ----------------
__global__ void khist(const int* __restrict__ edges, int* __restrict__ cnt, int T) {
  int t = blockIdx.x * 256 + threadIdx.x;
  if (t < T) {
    atomicAdd(&cnt[edges[2 * t]], 1);
    atomicAdd(&cnt[edges[2 * t + 1]], 1);
  }
}

// two-level scan
__global__ void kscan1(const int* __restrict__ cnt, int* __restrict__ offs,
                       int* __restrict__ bsum, int O) {
  __shared__ int buf[1024];
  int tid = threadIdx.x;
  int i = (blockIdx.x << 10) + tid;
  int v = (i < O) ? cnt[i] : 0;
  buf[tid] = v;
  __syncthreads();
  for (int d = 1; d < 1024; d <<= 1) {
    int t = (tid >= d) ? buf[tid - d] : 0;
    __syncthreads();
    buf[tid] += t;
    __syncthreads();
  }
  if (i < O) offs[i] = buf[tid] - v;
  if (tid == 1023) bsum[blockIdx.x] = buf[1023];
}

__global__ void kscan2(const int* __restrict__ bsum, int* __restrict__ bbase,
                       int nb, int* __restrict__ offs, int O) {
  __shared__ int buf[1024];
  int tid = threadIdx.x;
  int v = (tid < nb) ? bsum[tid] : 0;
  buf[tid] = v;
  __syncthreads();
  for (int d = 1; d < 1024; d <<= 1) {
    int t = (tid >= d) ? buf[tid - d] : 0;
    __syncthreads();
    buf[tid] += t;
    __syncthreads();
  }
  if (tid < nb) bbase[tid] = buf[tid] - v;
  if (tid == 1023) offs[O] = buf[1023];
}

// kscan3 also initializes the slot cursor (fused former kcursor)
__global__ void kscan3(int* __restrict__ offs, const int* __restrict__ bbase,
                       int* __restrict__ cur, int O) {
  int i = blockIdx.x * 256 + threadIdx.x;
  if (i < O) {
    int v = offs[i] + bbase[i >> 10];
    offs[i] = v;
    cur[i] = v;
  }
}

__global__ void kslot(const int* __restrict__ edges, int* __restrict__ cur,
                      int* __restrict__ slot_s, int* __restrict__ slot_o, int T) {
  int t = blockIdx.x * 256 + threadIdx.x;
  if (t < T) {
    slot_s[t] = atomicAdd(&cur[edges[2 * t]], 1);
    slot_o[t] = atomicAdd(&cur[edges[2 * t + 1]], 1);
  }
}

// ---------------- phase A: per-triple MLP + scatter (CSR or atomic) ----------------
// 256 threads (4 waves), MB=32. GEMM1 covers 8 column tiles in TWO register-resident
// passes per wave (acc0 for tile `wave`, acc1 for tile `wave+4`); all h-writes are
// deferred until after a barrier, so the cur/h LDS union is race-free at 40KB.
template <bool CSR>
__global__ __launch_bounds__(256, 2) void phaseA(
    const float* __restrict__ obj,             // [O][128] f32
    const float* __restrict__ pred,            // [T][128] f32
    const int* __restrict__ edges,             // [T][2]
    const float* __restrict__ b1a,             // [512] f32
    const float* __restrict__ b1b,             // [1152] f32
    const __hip_bfloat16* __restrict__ W1aP,   // packed GEMM1 weights
    const __hip_bfloat16* __restrict__ W1bP,   // packed GEMM2 weights
    float* __restrict__ pooled,                // [O][512] f32  (atomic mode)
    float* __restrict__ counts,                // [O] f32       (atomic mode)
    const int* __restrict__ slot_s,            // [T]           (CSR mode)
    const int* __restrict__ slot_o,            // [T]           (CSR mode)
    __hip_bfloat16* __restrict__ gathered,     // [2T+pad][512] bf16 (CSR mode)
    float* __restrict__ out_p,                 // [T][128] f32
    int Tn)
{
  __shared__ __align__(16) char lds[40960];
  const int tid  = threadIdx.x;
  const int lane = tid & 63;
  const int wave = tid >> 6;
  const int l15  = lane & 15;
  const int lg   = lane >> 4;
  const int t0   = blockIdx.x * MB;
  const int dump = 2 * Tn;   // scratch row for tail-invalid slots

  if constexpr (!CSR) {
    if (tid < MB && t0 + tid < Tn) {
      int s = edges[(t0 + tid) * 2 + 0];
      int o = edges[(t0 + tid) * 2 + 1];
      atomicAdd(&counts[s], 1.0f);
      atomicAdd(&counts[o], 1.0f);
    }
  }

  // gather cur = [obj[s] | pred | obj[o]] : 32 rows x 384 f32 -> bf16 LDS, swizzled
  // 32 rows * 96 float4-chunks = 3072 / 256 = 12 iters
  #pragma unroll
  for (int i = 0; i < 12; ++i) {
    int c   = tid + i * 256;
    int row = c / 96;
    int ch  = c - row * 96;
    int k0  = ch * 4;
    int rg  = t0 + row;
    if (rg >= Tn) rg = Tn - 1;          // clamp (outputs of tail rows discarded)
    const float* src;
    if (k0 < 128) {
      int s = edges[rg * 2 + 0];
      src = obj + (size_t)s * DIN + k0;
    } else if (k0 < 256) {
      src = pred + (size_t)rg * DIN + (k0 - 128);
    } else {
      int o = edges[rg * 2 + 1];
      src = obj + (size_t)o * DIN + (k0 - 256);
    }
    float4 v = *reinterpret_cast<const float4*>(src);
    uint2 val;
    val.x = (unsigned)bfbits(v.x) | ((unsigned)bfbits(v.y) << 16);
    val.y = (unsigned)bfbits(v.z) | ((unsigned)bfbits(v.w) << 16);
    int off = (row * 768 + ch * 8) ^ ((row & 7) << 4);
    *reinterpret_cast<uint2*>(lds + off) = val;
  }
  __syncthreads();

  // GEMM1: h = relu(cur @ W1a + b1a); 8 col-tiles over 4 waves = 2 register passes
  const facc fz = {0.f, 0.f, 0.f, 0.f};
  facc acc0[2][4], acc1[2][4];
  #pragma unroll
  for (int a = 0; a < 2; ++a)
    #pragma unroll
    for (int b = 0; b < 4; ++b) { acc0[a][b] = fz; acc1[a][b] = fz; }

  pipeGemm<12, 2, 768>((const char*)W1aP + (size_t)wave * 49152 + lane * 16,
                       lds, l15, lg, acc0);
  pipeGemm<12, 2, 768>((const char*)W1aP + (size_t)(wave + 4) * 49152 + lane * 16,
                       lds, l15, lg, acc1);
  __syncthreads();   // ALL waves done reading cur; union area becomes h

  #pragma unroll
  for (int p = 0; p < 2; ++p) {
    const int n0 = (wave + p * 4) * 64;
    #pragma unroll
    for (int nf = 0; nf < 4; ++nf) {
      int n = n0 + nf * 16 + l15;
      float bias = b1a[n];
      #pragma unroll
      for (int mf = 0; mf < 2; ++mf) {
        #pragma unroll
        for (int i = 0; i < 4; ++i) {
          float v = (p ? acc1[mf][nf][i] : acc0[mf][nf][i]) + bias;
          v = v > 0.f ? v : 0.f;
          int row = mf * 16 + lg * 4 + i;
          int off = (row * 1024 + n * 2) ^ ((row & 7) << 4);
          *reinterpret_cast<__hip_bfloat16*>(lds + off) = __float2bfloat16(v);
        }
      }
    }
  }
  __syncthreads();   // all 512 h columns written

  // GEMM2: new_t = relu(h @ W1b + b1b); 18 col-tiles of 64, 4 waves round-robin
  char* stg = lds + STG_BASE + wave * 2048;
  for (int nt = wave; nt < 18; nt += 4) {
    int nn0 = nt * 64;
    facc a2[2][4];
    #pragma unroll
    for (int a = 0; a < 2; ++a)
      #pragma unroll
      for (int b = 0; b < 4; ++b) a2[a][b] = fz;

    pipeGemm<16, 2, 1024>((const char*)W1bP + (size_t)nt * 65536 + lane * 16,
                          lds, l15, lg, a2);

    float bias[4];
    #pragma unroll
    for (int nf = 0; nf < 4; ++nf) bias[nf] = b1b[nn0 + nf * 16 + l15];

    if constexpr (CSR) {
      if (nn0 == 512 || nn0 == 576) {
        // pred output tile: direct f32 stores
        #pragma unroll
        for (int mf = 0; mf < 2; ++mf) {
          #pragma unroll
          for (int i = 0; i < 4; ++i) {
            int row = mf * 16 + lg * 4 + i;
            int t   = t0 + row;
            if (t < Tn) {
              #pragma unroll
              for (int nf = 0; nf < 4; ++nf) {
                int n = nn0 + nf * 16 + l15;
                float v = a2[mf][nf][i] + bias[nf];
                v = v > 0.f ? v : 0.f;
                __builtin_nontemporal_store(v, out_p + (size_t)t * DOUT + (n - 512));
              }
            }
          }
        }
      } else {
        // s-tile or o-tile: transpose through per-wave stage, full-line nt stores
        const bool is_s  = (nn0 < 512);
        const int coloff = is_s ? nn0 : (nn0 - 640);
        const int* slots = is_s ? slot_s : slot_o;
        int slotreg[4];
        #pragma unroll
        for (int j = 0; j < 4; ++j) {
          int rg = t0 + j * 8 + (lane >> 3);
          slotreg[j] = (rg < Tn) ? slots[rg] : dump;
        }
        #pragma unroll
        for (int mf = 0; mf < 2; ++mf) {
          // stage 16 rows x 64 cols bf16 (swizzled within 128B rows)
          #pragma unroll
          for (int nf = 0; nf < 4; ++nf) {
            #pragma unroll
            for (int i = 0; i < 4; ++i) {
              float v = a2[mf][nf][i] + bias[nf];
              v = v > 0.f ? v : 0.f;
              int lrow = lg * 4 + i;
              int off = (lrow * 128 + (nf * 16 + l15) * 2) ^ ((lrow & 7) << 4);
              *reinterpret_cast<__hip_bfloat16*>(stg + off) = __float2bfloat16(v);
            }
          }
          asm volatile("s_waitcnt lgkmcnt(0)" ::: "memory");
          // read back row-contiguous, store 8 lanes x 16B = 128B line segments
          #pragma unroll
          for (int t = 0; t < 2; ++t) {
            int r16   = t * 8 + (lane >> 3);
            int chunk = lane & 7;
            int off = (r16 * 128 + chunk * 16) ^ ((r16 & 7) << 4);
            uifrag val = *reinterpret_cast<const uifrag*>(stg + off);
            int slot = slotreg[mf * 2 + t];
            char* dst = (char*)gathered + (size_t)slot * 1024 + coloff * 2 + chunk * 16;
            __builtin_nontemporal_store(val, reinterpret_cast<uifrag*>(dst));
          }
          asm volatile("s_waitcnt lgkmcnt(0)" ::: "memory");
        }
      }
    } else {
      #pragma unroll
      for (int mf = 0; mf < 2; ++mf) {
        #pragma unroll
        for (int i = 0; i < 4; ++i) {
          int row = mf * 16 + lg * 4 + i;
          int t   = t0 + row;
          if (t < Tn) {
            if (nn0 < 512) {
              size_t base = (size_t)edges[2 * t] * HDIM;
              #pragma unroll
              for (int nf = 0; nf < 4; ++nf) {
                int n = nn0 + nf * 16 + l15;
                float v = a2[mf][nf][i] + bias[nf];
                v = v > 0.f ? v : 0.f;
                atomicAdd(&pooled[base + n], v);
              }
            } else if (nn0 < 640) {
              #pragma unroll
              for (int nf = 0; nf < 4; ++nf) {
                int n = nn0 + nf * 16 + l15;
                float v = a2[mf][nf][i] + bias[nf];
                v = v > 0.f ? v : 0.f;
                out_p[(size_t)t * DOUT + (n - 512)] = v;
              }
            } else {
              size_t base = (size_t)edges[2 * t + 1] * HDIM;
              #pragma unroll
              for (int nf = 0; nf < 4; ++nf) {
                int n = nn0 + nf * 16 + l15;
                float v = a2[mf][nf][i] + bias[nf];
                v = v > 0.f ? v : 0.f;
                atomicAdd(&pooled[base + (n - 640)], v);
              }
            }
          }
        }
      }
    }
  }
}

// ---------------- shared tail: GEMM3 + GEMM4 from staged LDS A-tile ----------------
__device__ __forceinline__ void mlp2_tail(
    char* lds, const float* __restrict__ b2a, const float* __restrict__ b2b,
    const __hip_bfloat16* __restrict__ W2aT, const __hip_bfloat16* __restrict__ W2bT,
    float* __restrict__ out_obj, int o0, int On)
{
  const int tid  = threadIdx.x;
  const int lane = tid & 63;
  const int wave = tid >> 6;
  const int l15  = lane & 15;
  const int lg   = lane >> 4;

  const facc fz = {0.f, 0.f, 0.f, 0.f};
  facc acc[4][4];
  #pragma unroll
  for (int a = 0; a < 4; ++a)
    #pragma unroll
    for (int b = 0; b < 4; ++b) acc[a][b] = fz;

  const int n0 = wave * 64;
  {
    const __hip_bfloat16* wb = W2aT + (size_t)(n0 + l15) * HDIM + lg * 8;
    bfrag bb0[4], bb1[4];
    #pragma unroll
    for (int nf = 0; nf < 4; ++nf)
      bb0[nf] = *reinterpret_cast<const bfrag*>(wb + (size_t)nf * 16 * HDIM);

    auto step3 = [&](int ks, bfrag* bbuf) {
      int k0 = ks * 32 + lg * 8;
      bfrag af[4];
      #pragma unroll
      for (int mf = 0; mf < 4; ++mf) {
        int row = mf * 16 + l15;
        int off = (row * 1024 + k0 * 2) ^ ((row & 7) << 4);
        af[mf] = *reinterpret_cast<const bfrag*>(lds + off);
      }
      #pragma unroll
      for (int mf = 0; mf < 4; ++mf)
        #pragma unroll
        for (int nf = 0; nf < 4; ++nf)
          acc[mf][nf] = mfma16(af[mf], bbuf[nf], acc[mf][nf]);
    };

    #pragma unroll
    for (int kp = 0; kp < 8; ++kp) {
      #pragma unroll
      for (int nf = 0; nf < 4; ++nf)
        bb1[nf] = *reinterpret_cast<const bfrag*>(wb + (size_t)nf * 16 * HDIM + (2 * kp + 1) * 32);
      step3(2 * kp, bb0);
      if (kp < 7) {
        #pragma unroll
        for (int nf = 0; nf < 4; ++nf)
          bb0[nf] = *reinterpret_cast<const bfrag*>(wb + (size_t)nf * 16 * HDIM + (2 * kp + 2) * 32);
      }
      step3(2 * kp + 1, bb1);
    }
  }
  __syncthreads();   // A consumed; lds becomes h2

  #pragma unroll
  for (int nf = 0; nf < 4; ++nf) {
    int n = n0 + nf * 16 + l15;
    float bias = b2a[n];
    #pragma unroll
    for (int mf = 0; mf < 4; ++mf) {
      #pragma unroll
      for (int i = 0; i < 4; ++i) {
        float v = acc[mf][nf][i] + bias;
        v = v > 0.f ? v : 0.f;
        int row = mf * 16 + lg * 4 + i;
        int off = (row * 1024 + n * 2) ^ ((row & 7) << 4);
        *reinterpret_cast<__hip_bfloat16*>(lds + off) = __float2bfloat16(v);
      }
    }
  }
  __syncthreads();

  facc a4[4];
  #pragma unroll
  for (int a = 0; a < 4; ++a) a4[a] = fz;
  const int n4 = wave * 16;
  for (int ks = 0; ks < 16; ++ks) {
    int k0 = ks * 32 + lg * 8;
    bfrag bfr = *reinterpret_cast<const bfrag*>(W2bT + (size_t)(n4 + l15) * HDIM + k0);
    #pragma unroll
    for (int mf = 0; mf < 4; ++mf) {
      int row = mf * 16 + l15;
      int off = (row * 1024 + k0 * 2) ^ ((row & 7) << 4);
      bfrag afr = *reinterpret_cast<const bfrag*>(lds + off);
      a4[mf] = mfma16(afr, bfr, a4[mf]);
    }
  }
  {
    int n = n4 + l15;
    float bias = b2b[n];
    #pragma unroll
    for (int mf = 0; mf < 4; ++mf)
      #pragma unroll
      for (int i = 0; i < 4; ++i) {
        float v = a4[mf][i] + bias;
        v = v > 0.f ? v : 0.f;
        int row = o0 + mf * 16 + lg * 4 + i;
        if (row < On) out_obj[(size_t)row * DOUT + n] = v;
      }
  }
}

// ---------------- phase B (atomic mode): pooled f32 -> object MLP ----------------
__global__ __launch_bounds__(512, 4) void phaseB_atomic(
    const float* __restrict__ pooled,
    const float* __restrict__ counts,
    const float* __restrict__ b2a,
    const float* __restrict__ b2b,
    const __hip_bfloat16* __restrict__ W2aT,
    const __hip_bfloat16* __restrict__ W2bT,
    float* __restrict__ out_obj,
    int On)
{
  __shared__ __align__(16) char lds[65536];
  const int tid = threadIdx.x;
  const int o0  = blockIdx.x * 64;

  #pragma unroll
  for (int i = 0; i < 16; ++i) {
    int c   = tid + i * 512;
    int row = c >> 7;
    int c4  = c & 127;
    int r   = o0 + row;
    facc v = {0.f, 0.f, 0.f, 0.f};
    if (r < On) {
      v = *reinterpret_cast<const facc*>(pooled + (size_t)r * HDIM + c4 * 4);
      float cc = counts[r];
      cc = cc < 1.f ? 1.f : cc;
      cc = cc > (float)On ? (float)On : cc;
      v *= (1.f / cc);
    }
    uint2 val;
    val.x = (unsigned)bfbits(v[0]) | ((unsigned)bfbits(v[1]) << 16);
    val.y = (unsigned)bfbits(v[2]) | ((unsigned)bfbits(v[3]) << 16);
    int off = (row * 1024 + c4 * 8) ^ ((row & 7) << 4);
    *reinterpret_cast<uint2*>(lds + off) = val;
  }
  __syncthreads();
  mlp2_tail(lds, b2a, b2b, W2aT, W2bT, out_obj, o0, On);
}

// ---------------- phase B (CSR mode): sum runs -> object MLP ----------------
__global__ __launch_bounds__(512, 4) void phaseB_csr(
    const __hip_bfloat16* __restrict__ gathered,  // [2T+pad][512] bf16
    const int* __restrict__ offs,                 // [O+1]
    const float* __restrict__ b2a,
    const float* __restrict__ b2b,
    const __hip_bfloat16* __restrict__ W2aT,
    const __hip_bfloat16* __restrict__ W2bT,
    float* __restrict__ out_obj,
    int On)
{
  __shared__ __align__(16) char lds[65536];
  const int tid  = threadIdx.x;
  const int lane = tid & 63;
  const int wave = tid >> 6;
  const int o0   = blockIdx.x * 64;

  for (int jj = 0; jj < 8; ++jj) {
    int row = wave * 8 + jj;
    int r   = o0 + row;
    float acc[8] = {0.f, 0.f, 0.f, 0.f, 0.f, 0.f, 0.f, 0.f};
    float inv = 0.f;
    if (r < On) {
      int st = offs[r], en = offs[r + 1];
      int run = en - st;
      const char* gp = (const char*)gathered + (size_t)st * 1024 + lane * 16;
      // batch-8: issue up to 8 independent row loads, drain with vmcnt(0), consume.
      for (int i = 0; i < run; i += 8) {
        int m = run - i;
        m = m > 8 ? 8 : m;
        uifrag w0 = {0,0,0,0}, w1 = {0,0,0,0}, w2 = {0,0,0,0}, w3 = {0,0,0,0};
        uifrag w4 = {0,0,0,0}, w5 = {0,0,0,0}, w6 = {0,0,0,0}, w7 = {0,0,0,0};
        const char* bp = gp + (size_t)i * 1024;
        GL1(w0, bp);
        if (m > 1) { GL1(w1, bp + 1024); }
        if (m > 2) { GL1(w2, bp + 2048); }
        if (m > 3) { GL1(w3, bp + 3072); }
        if (m > 4) { GL1(w4, bp + 4096); }
        if (m > 5) { GL1(w5, bp + 5120); }
        if (m > 6) { GL1(w6, bp + 6144); }
        if (m > 7) { GL1(w7, bp + 7168); }
        asm volatile("s_waitcnt vmcnt(0)"
                     : "+v"(w0), "+v"(w1), "+v"(w2), "+v"(w3),
                       "+v"(w4), "+v"(w5), "+v"(w6), "+v"(w7) :: "memory");
        {
          bfrag bv = __builtin_bit_cast(bfrag, w0);
          #pragma unroll
          for (int q = 0; q < 8; ++q) acc[q] += b2f(bv[q]);
        }
        if (m > 1) {
          bfrag bv = __builtin_bit_cast(bfrag, w1);
          #pragma unroll
          for (int q = 0; q < 8; ++q) acc[q] += b2f(bv[q]);
        }
        if (m > 2) {
          bfrag bv = __builtin_bit_cast(bfrag, w2);
          #pragma unroll
          for (int q = 0; q < 8; ++q) acc[q] += b2f(bv[q]);
        }
        if (m > 3) {
          bfrag bv = __builtin_bit_cast(bfrag, w3);
          #pragma unroll
          for (int q = 0; q < 8; ++q) acc[q] += b2f(bv[q]);
        }
        if (m > 4) {
          bfrag bv = __builtin_bit_cast(bfrag, w4);
          #pragma unroll
          for (int q = 0; q < 8; ++q) acc[q] += b2f(bv[q]);
        }
        if (m > 5) {
          bfrag bv = __builtin_bit_cast(bfrag, w5);
          #pragma unroll
          for (int q = 0; q < 8; ++q) acc[q] += b2f(bv[q]);
        }
        if (m > 6) {
          bfrag bv = __builtin_bit_cast(bfrag, w6);
          #pragma unroll
          for (int q = 0; q < 8; ++q) acc[q] += b2f(bv[q]);
        }
        if (m > 7) {
          bfrag bv = __builtin_bit_cast(bfrag, w7);
          #pragma unroll
          for (int q = 0; q < 8; ++q) acc[q] += b2f(bv[q]);
        }
      }
      int cc = run;
      cc = cc < 1 ? 1 : cc;
      cc = cc > On ? On : cc;
      inv = 1.f / (float)cc;
    }
    unsigned short t[8];
    #pragma unroll
    for (int q = 0; q < 8; ++q) t[q] = bfbits(acc[q] * inv);
    uifrag val;
    val.x = (unsigned)t[0] | ((unsigned)t[1] << 16);
    val.y = (unsigned)t[2] | ((unsigned)t[3] << 16);
    val.z = (unsigned)t[4] | ((unsigned)t[5] << 16);
    val.w = (unsigned)t[6] | ((unsigned)t[7] << 16);
    int off = (row * 1024 + lane * 16) ^ ((row & 7) << 4);
    *reinterpret_cast<uifrag*>(lds + off) = val;
  }
  __syncthreads();
  mlp2_tail(lds, b2a, b2b, W2aT, W2bT, out_obj, o0, On);
}

extern "C" void kernel_launch(void* const* d_in, const int* in_sizes, int n_in,
                              void* d_out, int out_size, void* d_ws, size_t ws_size,
                              hipStream_t stream) {
  const float* obj   = (const float*)d_in[0];
  const float* pred  = (const float*)d_in[1];
  const int*   edges = (const int*)d_in[2];
  const float* W1a   = (const float*)d_in[3];
  const float* b1a   = (const float*)d_in[4];
  const float* W1b   = (const float*)d_in[5];
  const float* b1b   = (const float*)d_in[6];
  const float* W2a   = (const float*)d_in[7];
  const float* b2a   = (const float*)d_in[8];
  const float* W2b   = (const float*)d_in[9];
  const float* b2b   = (const float*)d_in[10];

  const int On = in_sizes[0] / DIN;   // 50000
  const int Tn = in_sizes[1] / DIN;   // 200000

  char* ws = (char*)d_ws;

  __hip_bfloat16* W1aP = (__hip_bfloat16*)ws;                   // packed [384*512]
  __hip_bfloat16* W1bP = W1aP + (size_t)HDIM * K1;              // packed [512*1152]
  __hip_bfloat16* W2aT = W1bP + (size_t)N2 * HDIM;              // [512][512]
  __hip_bfloat16* W2bT = W2aT + (size_t)HDIM * HDIM;            // [128][512]
  size_t wend = ((((size_t)(HDIM * K1 + N2 * HDIM + HDIM * HDIM + HDIM * DOUT)) * 2) + 255) & ~(size_t)255;

  // CSR layout
  int*   cnt    = (int*)(ws + wend);
  int*   offs   = cnt + On;              // [On+1]
  int*   cur    = offs + (On + 1);
  int*   slot_s = cur + On;
  int*   slot_o = slot_s + Tn;
  int*   bsum   = slot_o + Tn;           // [64]
  int*   bbase  = bsum + 64;             // [64]
  size_t gath_off = (wend + ((size_t)(3 * On + 1 + 2 * Tn + 128)) * 4 + 255) & ~(size_t)255;
  __hip_bfloat16* gathered = (__hip_bfloat16*)(ws + gath_off);
  size_t need_csr = gath_off + (size_t)(2 * Tn + 64) * HDIM * 2;  // +dump rows

  // atomic layout (fallback)
  float* pooled  = (float*)(ws + wend);
  float* countsf = pooled + (size_t)On * HDIM;

  bool use_csr = (ws_size >= need_csr);

  {
    int n;
    n = K1 * HDIM;   kpack<<<(n + 255) / 256, 256, 0, stream>>>(W1a, W1aP, K1, HDIM);
    n = HDIM * N2;   kpack<<<(n + 255) / 256, 256, 0, stream>>>(W1b, W1bP, HDIM, N2);
    n = HDIM * HDIM; ktranspose<<<(n + 255) / 256, 256, 0, stream>>>(W2a, W2aT, HDIM, HDIM);
    n = HDIM * DOUT; ktranspose<<<(n + 255) / 256, 256, 0, stream>>>(W2b, W2bT, HDIM, DOUT);
  }

  float* out_obj = (float*)d_out;
  float* out_p   = out_obj + (size_t)On * DOUT;

  const int gridA = (Tn + MB - 1) / MB;
  const int nb    = (On + 1023) >> 10;   // scan blocks (<= 64 for On <= 65536)

  if (use_csr) {
    (void)hipMemsetAsync(cnt, 0, (size_t)On * 4, stream);
    khist <<<(Tn + 255) / 256, 256, 0, stream>>>(edges, cnt, Tn);
    kscan1<<<nb, 1024, 0, stream>>>(cnt, offs, bsum, On);
    kscan2<<<1, 1024, 0, stream>>>(bsum, bbase, nb, offs, On);
    kscan3<<<(On + 255) / 256, 256, 0, stream>>>(offs, bbase, cur, On);
    kslot <<<(Tn + 255) / 256, 256, 0, stream>>>(edges, cur, slot_s, slot_o, Tn);
    phaseA<true><<<gridA, 256, 0, stream>>>(obj, pred, edges, b1a, b1b, W1aP, W1bP,
                                            nullptr, nullptr, slot_s, slot_o, gathered,
                                            out_p, Tn);
    phaseB_csr<<<(On + 63) / 64, 512, 0, stream>>>(gathered, offs, b2a, b2b, W2aT, W2bT,
                                                   out_obj, On);
  } else {
    (void)hipMemsetAsync(pooled, 0, (size_t)On * HDIM * 4 + (size_t)On * 4, stream);
    phaseA<false><<<gridA, 256, 0, stream>>>(obj, pred, edges, b1a, b1b, W1aP, W1bP,
                                             pooled, countsf, nullptr, nullptr, nullptr,
                                             out_p, Tn);
    phaseB_atomic<<<(On + 63) / 64, 512, 0, stream>>>(pooled, countsf, b2a, b2b, W2aT, W2bT,
                                                      out_obj, On);
  }
}

// Round 19
// 749.393 us; speedup vs baseline: 1.0762x; 1.0762x over previous
//
#include <hip/hip_runtime.h>
#include <hip/hip_bf16.h>

typedef __attribute__((ext_vector_type(8))) short bfrag;   // 8 bf16 = 4 VGPR
typedef __attribute__((ext_vector_type(4))) float facc;    // 4 f32 acc
typedef __attribute__((ext_vector_type(4))) unsigned int uifrag; // 16B vector

#define DIN   128
#define HDIM  512
#define DOUT  128
#define K1    384
#define N2    1152
#define MB    48      // triples per block (h tile 48KB + 16KB stage = 64KB LDS)

__device__ __forceinline__ facc mfma16(bfrag a, bfrag b, facc c) {
  return __builtin_amdgcn_mfma_f32_16x16x32_bf16(a, b, c, 0, 0, 0);
}

__device__ __forceinline__ unsigned short bfbits(float x) {
  __hip_bfloat16 b = __float2bfloat16(x);
  return __builtin_bit_cast(unsigned short, b);
}

__device__ __forceinline__ float b2f(short u) {
  return __bfloat162float(__builtin_bit_cast(__hip_bfloat16, (unsigned short)u));
}

// issue 4 coalesced 16B loads (one 4KB step-chunk) into buffer B
#define GLOAD4(B, base)                                                              \
  asm volatile("global_load_dwordx4 %0, %1, off"             : "=v"(B[0]) : "v"(base)); \
  asm volatile("global_load_dwordx4 %0, %1, off offset:1024" : "=v"(B[1]) : "v"(base)); \
  asm volatile("global_load_dwordx4 %0, %1, off offset:2048" : "=v"(B[2]) : "v"(base)); \
  asm volatile("global_load_dwordx4 %0, %1, off offset:3072" : "=v"(B[3]) : "v"(base));

// wait until <= N vmem outstanding, with data-dep on the 4 consumed fragment regs
#define BWAITN(B, N) asm volatile("s_waitcnt vmcnt(" #N ")"                          \
    : "+v"(B[0]), "+v"(B[1]), "+v"(B[2]), "+v"(B[3]) :: "memory")

// single 16B load (phaseB run loop)
#define GL1(D, addr) asm volatile("global_load_dwordx4 %0, %1, off" : "=v"(D) : "v"(addr))

// ---------------- pipelined GEMM inner loop: depth-3 B prefetch ----------------
// NS k-steps; MF m-fragments from LDS (stride STRIDE bytes); packed weights at pw.
// Requires >= ~176 unified registers: ONLY call from kernels with
// __launch_bounds__(512, 2) (256-VGPR budget) — at a 128 cap the allocator
// spills in-flight asm registers (round-9/10 corruption).
template <int NS, int MF, int STRIDE>
__device__ __forceinline__ void pipeGemm(const char* pw, const char* lds,
                                         int l15, int lg, facc (&acc)[MF][4]) {
  uifrag B[4][4];
  GLOAD4(B[0], pw);
  GLOAD4(B[1], pw + 4096);
  GLOAD4(B[2], pw + 8192);
  #pragma unroll
  for (int ks = 0; ks < NS; ++ks) {
    uifrag (&cur)[4] = B[ks & 3];
    if (ks + 3 < NS) {
      GLOAD4(B[(ks + 3) & 3], pw + (size_t)(ks + 3) * 4096);
      BWAITN(cur, 12);
    } else if (ks + 2 < NS) {
      BWAITN(cur, 8);
    } else if (ks + 1 < NS) {
      BWAITN(cur, 4);
    } else {
      BWAITN(cur, 0);
    }
    int k0 = ks * 32 + lg * 8;
    bfrag af[MF];
    #pragma unroll
    for (int mf = 0; mf < MF; ++mf) {
      int row = mf * 16 + l15;
      int off = (row * STRIDE + k0 * 2) ^ ((row & 7) << 4);
      af[mf] = *reinterpret_cast<const bfrag*>(lds + off);
    }
    #pragma unroll
    for (int mf = 0; mf < MF; ++mf)
      #pragma unroll
      for (int nf = 0; nf < 4; ++nf)
        acc[mf][nf] = mfma16(af[mf], __builtin_bit_cast(bfrag, cur[nf]), acc[mf][nf]);
  }
}

// ---------------- weight transpose + f32->bf16 (per call; tiny) ----------------
__global__ void ktranspose(const float* __restrict__ in,
                           __hip_bfloat16* __restrict__ out, int rows, int cols) {
  int idx = blockIdx.x * 256 + threadIdx.x;
  if (idx < rows * cols) {
    int i = idx / cols;
    int j = idx - i * cols;
    out[(size_t)j * rows + i] = __float2bfloat16(in[idx]);
  }
}

// ---------------- weight pack: [K][N] f32 -> per-(tile64,ks,frag16) 1KB chunks ----
__global__ void kpack(const float* __restrict__ in, __hip_bfloat16* __restrict__ out,
                      int K, int N) {
  int idx = blockIdx.x * 256 + threadIdx.x;
  if (idx >= K * N) return;
  int k = idx / N;
  int n = idx - k * N;
  int ks = k >> 5, lg = (k >> 3) & 3, j = k & 7;
  int w = n >> 6, nf = (n >> 4) & 3, l15 = n & 15;
  int nsteps = K >> 5;
  size_t dst = ((size_t)(w * nsteps + ks) * 4 + nf) * 512 + (lg * 16 + l15) * 8 + j;
  out[dst] = __float2bfloat16(in[idx]);
}

// ---------------- CSR build ----------------
__global__ void khist(const int* __restrict__ edges, int* __restrict__ cnt, int T) {
  int t = blockIdx.x * 256 + threadIdx.x;
  if (t < T) {
    atomicAdd(&cnt[edges[2 * t]], 1);
    atomicAdd(&cnt[edges[2 * t + 1]], 1);
  }
}

// two-level scan: kscan1 per-block local scan, kscan2 scans block sums, kscan3 adds
__global__ void kscan1(const int* __restrict__ cnt, int* __restrict__ offs,
                       int* __restrict__ bsum, int O) {
  __shared__ int buf[1024];
  int tid = threadIdx.x;
  int i = (blockIdx.x << 10) + tid;
  int v = (i < O) ? cnt[i] : 0;
  buf[tid] = v;
  __syncthreads();
  for (int d = 1; d < 1024; d <<= 1) {
    int t = (tid >= d) ? buf[tid - d] : 0;
    __syncthreads();
    buf[tid] += t;
    __syncthreads();
  }
  if (i < O) offs[i] = buf[tid] - v;
  if (tid == 1023) bsum[blockIdx.x] = buf[1023];
}

__global__ void kscan2(const int* __restrict__ bsum, int* __restrict__ bbase,
                       int nb, int* __restrict__ offs, int O) {
  __shared__ int buf[1024];
  int tid = threadIdx.x;
  int v = (tid < nb) ? bsum[tid] : 0;
  buf[tid] = v;
  __syncthreads();
  for (int d = 1; d < 1024; d <<= 1) {
    int t = (tid >= d) ? buf[tid - d] : 0;
    __syncthreads();
    buf[tid] += t;
    __syncthreads();
  }
  if (tid < nb) bbase[tid] = buf[tid] - v;
  if (tid == 1023) offs[O] = buf[1023];
}

// kscan3 also initializes the slot cursor (fused former kcursor)
__global__ void kscan3(int* __restrict__ offs, const int* __restrict__ bbase,
                       int* __restrict__ cur, int O) {
  int i = blockIdx.x * 256 + threadIdx.x;
  if (i < O) {
    int v = offs[i] + bbase[i >> 10];
    offs[i] = v;
    cur[i] = v;
  }
}

__global__ void kslot(const int* __restrict__ edges, int* __restrict__ cur,
                      int* __restrict__ slot_s, int* __restrict__ slot_o, int T) {
  int t = blockIdx.x * 256 + threadIdx.x;
  if (t < T) {
    slot_s[t] = atomicAdd(&cur[edges[2 * t]], 1);
    slot_o[t] = atomicAdd(&cur[edges[2 * t + 1]], 1);
  }
}

// ---------------- phase A: per-triple MLP + scatter (CSR or atomic) ----------------
// static LDS 64KB: [0, 48K) = cur (36KB) then h [48][512] bf16 (48KB, union)
//                  [48K, 64K) = per-wave 2KB transpose stage
// __launch_bounds__(512, 2): 256-VGPR budget so the depth-3 pipeline never spills;
// occupancy 1 block/CU — in-wave ILP replaces TLP.
template <bool CSR>
__global__ __launch_bounds__(512, 2) void phaseA(
    const float* __restrict__ obj,             // [O][128] f32
    const float* __restrict__ pred,            // [T][128] f32
    const int* __restrict__ edges,             // [T][2]
    const float* __restrict__ b1a,             // [512] f32
    const float* __restrict__ b1b,             // [1152] f32
    const __hip_bfloat16* __restrict__ W1aP,   // packed GEMM1 weights
    const __hip_bfloat16* __restrict__ W1bP,   // packed GEMM2 weights
    float* __restrict__ pooled,                // [O][512] f32  (atomic mode)
    float* __restrict__ counts,                // [O] f32       (atomic mode)
    const int* __restrict__ slot_s,            // [T]           (CSR mode)
    const int* __restrict__ slot_o,            // [T]           (CSR mode)
    __hip_bfloat16* __restrict__ gathered,     // [2T+pad][512] bf16 (CSR mode)
    float* __restrict__ out_p,                 // [T][128] f32
    int Tn)
{
  __shared__ __align__(16) char lds[65536];
  const int tid  = threadIdx.x;
  const int lane = tid & 63;
  const int wave = tid >> 6;
  const int l15  = lane & 15;
  const int lg   = lane >> 4;
  const int t0   = blockIdx.x * MB;
  const int dump = 2 * Tn;   // scratch row for tail-invalid slots

  if constexpr (!CSR) {
    if (tid < MB && t0 + tid < Tn) {
      int s = edges[(t0 + tid) * 2 + 0];
      int o = edges[(t0 + tid) * 2 + 1];
      atomicAdd(&counts[s], 1.0f);
      atomicAdd(&counts[o], 1.0f);
    }
  }

  // gather cur = [obj[s] | pred | obj[o]] : 48 rows x 384 f32 -> bf16 LDS, swizzled
  #pragma unroll
  for (int i = 0; i < 9; ++i) {
    int c   = tid + i * 512;
    int row = c / 96;
    int ch  = c - row * 96;
    int k0  = ch * 4;
    int rg  = t0 + row;
    if (rg >= Tn) rg = Tn - 1;          // clamp (outputs of tail rows discarded)
    const float* src;
    if (k0 < 128) {
      int s = edges[rg * 2 + 0];
      src = obj + (size_t)s * DIN + k0;
    } else if (k0 < 256) {
      src = pred + (size_t)rg * DIN + (k0 - 128);
    } else {
      int o = edges[rg * 2 + 1];
      src = obj + (size_t)o * DIN + (k0 - 256);
    }
    float4 v = *reinterpret_cast<const float4*>(src);
    uint2 val;
    val.x = (unsigned)bfbits(v.x) | ((unsigned)bfbits(v.y) << 16);
    val.y = (unsigned)bfbits(v.z) | ((unsigned)bfbits(v.w) << 16);
    int off = (row * 768 + ch * 8) ^ ((row & 7) << 4);
    *reinterpret_cast<uint2*>(lds + off) = val;
  }
  __syncthreads();

  // GEMM1: h = relu(cur @ W1a + b1a); wave w -> cols [64w, 64w+64)
  const facc fz = {0.f, 0.f, 0.f, 0.f};
  facc acc[3][4];
  #pragma unroll
  for (int a = 0; a < 3; ++a)
    #pragma unroll
    for (int b = 0; b < 4; ++b) acc[a][b] = fz;

  const int n0 = wave * 64;
  pipeGemm<12, 3, 768>((const char*)W1aP + (size_t)(wave * 48) * 1024 + lane * 16,
                       lds, l15, lg, acc);
  __syncthreads();   // cur fully consumed; lds becomes h [48][512] bf16

  #pragma unroll
  for (int nf = 0; nf < 4; ++nf) {
    int n = n0 + nf * 16 + l15;
    float bias = b1a[n];
    #pragma unroll
    for (int mf = 0; mf < 3; ++mf) {
      #pragma unroll
      for (int i = 0; i < 4; ++i) {
        float v = acc[mf][nf][i] + bias;
        v = v > 0.f ? v : 0.f;
        int row = mf * 16 + lg * 4 + i;
        int off = (row * 1024 + n * 2) ^ ((row & 7) << 4);
        *reinterpret_cast<__hip_bfloat16*>(lds + off) = __float2bfloat16(v);
      }
    }
  }
  __syncthreads();

  // GEMM2: new_t = relu(h @ W1b + b1b); 18 col-tiles of 64
  char* stg = lds + 49152 + wave * 2048;
  for (int nt = wave; nt < 18; nt += 8) {
    int nn0 = nt * 64;
    facc a2[3][4];
    #pragma unroll
    for (int a = 0; a < 3; ++a)
      #pragma unroll
      for (int b = 0; b < 4; ++b) a2[a][b] = fz;

    pipeGemm<16, 3, 1024>((const char*)W1bP + (size_t)(nt * 64) * 1024 + lane * 16,
                          lds, l15, lg, a2);

    float bias[4];
    #pragma unroll
    for (int nf = 0; nf < 4; ++nf) bias[nf] = b1b[nn0 + nf * 16 + l15];

    if constexpr (CSR) {
      if (nn0 == 512 || nn0 == 576) {
        // pred output tile: direct f32 stores
        #pragma unroll
        for (int mf = 0; mf < 3; ++mf) {
          #pragma unroll
          for (int i = 0; i < 4; ++i) {
            int row = mf * 16 + lg * 4 + i;
            int t   = t0 + row;
            if (t < Tn) {
              #pragma unroll
              for (int nf = 0; nf < 4; ++nf) {
                int n = nn0 + nf * 16 + l15;
                float v = a2[mf][nf][i] + bias[nf];
                v = v > 0.f ? v : 0.f;
                __builtin_nontemporal_store(v, out_p + (size_t)t * DOUT + (n - 512));
              }
            }
          }
        }
      } else {
        // s-tile or o-tile: transpose through per-wave stage, full-line nt stores
        const bool is_s  = (nn0 < 512);
        const int coloff = is_s ? nn0 : (nn0 - 640);
        const int* slots = is_s ? slot_s : slot_o;
        int slotreg[6];
        #pragma unroll
        for (int j = 0; j < 6; ++j) {
          int rg = t0 + j * 8 + (lane >> 3);
          slotreg[j] = (rg < Tn) ? slots[rg] : dump;
        }
        #pragma unroll
        for (int mf = 0; mf < 3; ++mf) {
          // stage 16 rows x 64 cols bf16 (swizzled within 128B rows)
          #pragma unroll
          for (int nf = 0; nf < 4; ++nf) {
            #pragma unroll
            for (int i = 0; i < 4; ++i) {
              float v = a2[mf][nf][i] + bias[nf];
              v = v > 0.f ? v : 0.f;
              int lrow = lg * 4 + i;
              int off = (lrow * 128 + (nf * 16 + l15) * 2) ^ ((lrow & 7) << 4);
              *reinterpret_cast<__hip_bfloat16*>(stg + off) = __float2bfloat16(v);
            }
          }
          asm volatile("s_waitcnt lgkmcnt(0)" ::: "memory");
          // read back row-contiguous, store 8 lanes x 16B = 128B line segments
          #pragma unroll
          for (int t = 0; t < 2; ++t) {
            int r16   = t * 8 + (lane >> 3);
            int chunk = lane & 7;
            int off = (r16 * 128 + chunk * 16) ^ ((r16 & 7) << 4);
            uifrag val = *reinterpret_cast<const uifrag*>(stg + off);
            int j = mf * 2 + t;
            int slot = slotreg[j];
            char* dst = (char*)gathered + (size_t)slot * 1024 + coloff * 2 + chunk * 16;
            __builtin_nontemporal_store(val, reinterpret_cast<uifrag*>(dst));
          }
          asm volatile("s_waitcnt lgkmcnt(0)" ::: "memory");
        }
      }
    } else {
      #pragma unroll
      for (int mf = 0; mf < 3; ++mf) {
        #pragma unroll
        for (int i = 0; i < 4; ++i) {
          int row = mf * 16 + lg * 4 + i;
          int t   = t0 + row;
          if (t < Tn) {
            if (nn0 < 512) {
              size_t base = (size_t)edges[2 * t] * HDIM;
              #pragma unroll
              for (int nf = 0; nf < 4; ++nf) {
                int n = nn0 + nf * 16 + l15;
                float v = a2[mf][nf][i] + bias[nf];
                v = v > 0.f ? v : 0.f;
                atomicAdd(&pooled[base + n], v);
              }
            } else if (nn0 < 640) {
              #pragma unroll
              for (int nf = 0; nf < 4; ++nf) {
                int n = nn0 + nf * 16 + l15;
                float v = a2[mf][nf][i] + bias[nf];
                v = v > 0.f ? v : 0.f;
                out_p[(size_t)t * DOUT + (n - 512)] = v;
              }
            } else {
              size_t base = (size_t)edges[2 * t + 1] * HDIM;
              #pragma unroll
              for (int nf = 0; nf < 4; ++nf) {
                int n = nn0 + nf * 16 + l15;
                float v = a2[mf][nf][i] + bias[nf];
                v = v > 0.f ? v : 0.f;
                atomicAdd(&pooled[base + (n - 640)], v);
              }
            }
          }
        }
      }
    }
  }
}

// ---------------- shared tail: GEMM3 + GEMM4 from staged LDS A-tile ----------------
__device__ __forceinline__ void mlp2_tail(
    char* lds, const float* __restrict__ b2a, const float* __restrict__ b2b,
    const __hip_bfloat16* __restrict__ W2aT, const __hip_bfloat16* __restrict__ W2bT,
    float* __restrict__ out_obj, int o0, int On)
{
  const int tid  = threadIdx.x;
  const int lane = tid & 63;
  const int wave = tid >> 6;
  const int l15  = lane & 15;
  const int lg   = lane >> 4;

  const facc fz = {0.f, 0.f, 0.f, 0.f};
  facc acc[4][4];
  #pragma unroll
  for (int a = 0; a < 4; ++a)
    #pragma unroll
    for (int b = 0; b < 4; ++b) acc[a][b] = fz;

  const int n0 = wave * 64;
  {
    const __hip_bfloat16* wb = W2aT + (size_t)(n0 + l15) * HDIM + lg * 8;
    bfrag bb0[4], bb1[4];
    #pragma unroll
    for (int nf = 0; nf < 4; ++nf)
      bb0[nf] = *reinterpret_cast<const bfrag*>(wb + (size_t)nf * 16 * HDIM);

    auto step3 = [&](int ks, bfrag* bbuf) {
      int k0 = ks * 32 + lg * 8;
      bfrag af[4];
      #pragma unroll
      for (int mf = 0; mf < 4; ++mf) {
        int row = mf * 16 + l15;
        int off = (row * 1024 + k0 * 2) ^ ((row & 7) << 4);
        af[mf] = *reinterpret_cast<const bfrag*>(lds + off);
      }
      #pragma unroll
      for (int mf = 0; mf < 4; ++mf)
        #pragma unroll
        for (int nf = 0; nf < 4; ++nf)
          acc[mf][nf] = mfma16(af[mf], bbuf[nf], acc[mf][nf]);
    };

    #pragma unroll
    for (int kp = 0; kp < 8; ++kp) {
      #pragma unroll
      for (int nf = 0; nf < 4; ++nf)
        bb1[nf] = *reinterpret_cast<const bfrag*>(wb + (size_t)nf * 16 * HDIM + (2 * kp + 1) * 32);
      step3(2 * kp, bb0);
      if (kp < 7) {
        #pragma unroll
        for (int nf = 0; nf < 4; ++nf)
          bb0[nf] = *reinterpret_cast<const bfrag*>(wb + (size_t)nf * 16 * HDIM + (2 * kp + 2) * 32);
      }
      step3(2 * kp + 1, bb1);
    }
  }
  __syncthreads();   // A consumed; lds becomes h2

  #pragma unroll
  for (int nf = 0; nf < 4; ++nf) {
    int n = n0 + nf * 16 + l15;
    float bias = b2a[n];
    #pragma unroll
    for (int mf = 0; mf < 4; ++mf) {
      #pragma unroll
      for (int i = 0; i < 4; ++i) {
        float v = acc[mf][nf][i] + bias;
        v = v > 0.f ? v : 0.f;
        int row = mf * 16 + lg * 4 + i;
        int off = (row * 1024 + n * 2) ^ ((row & 7) << 4);
        *reinterpret_cast<__hip_bfloat16*>(lds + off) = __float2bfloat16(v);
      }
    }
  }
  __syncthreads();

  facc a4[4];
  #pragma unroll
  for (int a = 0; a < 4; ++a) a4[a] = fz;
  const int n4 = wave * 16;
  for (int ks = 0; ks < 16; ++ks) {
    int k0 = ks * 32 + lg * 8;
    bfrag bfr = *reinterpret_cast<const bfrag*>(W2bT + (size_t)(n4 + l15) * HDIM + k0);
    #pragma unroll
    for (int mf = 0; mf < 4; ++mf) {
      int row = mf * 16 + l15;
      int off = (row * 1024 + k0 * 2) ^ ((row & 7) << 4);
      bfrag afr = *reinterpret_cast<const bfrag*>(lds + off);
      a4[mf] = mfma16(afr, bfr, a4[mf]);
    }
  }
  {
    int n = n4 + l15;
    float bias = b2b[n];
    #pragma unroll
    for (int mf = 0; mf < 4; ++mf)
      #pragma unroll
      for (int i = 0; i < 4; ++i) {
        float v = a4[mf][i] + bias;
        v = v > 0.f ? v : 0.f;
        int row = o0 + mf * 16 + lg * 4 + i;
        if (row < On) out_obj[(size_t)row * DOUT + n] = v;
      }
  }
}

// ---------------- phase B (atomic mode): pooled f32 -> object MLP ----------------
__global__ __launch_bounds__(512, 4) void phaseB_atomic(
    const float* __restrict__ pooled,
    const float* __restrict__ counts,
    const float* __restrict__ b2a,
    const float* __restrict__ b2b,
    const __hip_bfloat16* __restrict__ W2aT,
    const __hip_bfloat16* __restrict__ W2bT,
    float* __restrict__ out_obj,
    int On)
{
  __shared__ __align__(16) char lds[65536];
  const int tid = threadIdx.x;
  const int o0  = blockIdx.x * 64;

  #pragma unroll
  for (int i = 0; i < 16; ++i) {
    int c   = tid + i * 512;
    int row = c >> 7;
    int c4  = c & 127;
    int r   = o0 + row;
    facc v = {0.f, 0.f, 0.f, 0.f};
    if (r < On) {
      v = *reinterpret_cast<const facc*>(pooled + (size_t)r * HDIM + c4 * 4);
      float cc = counts[r];
      cc = cc < 1.f ? 1.f : cc;
      cc = cc > (float)On ? (float)On : cc;
      v *= (1.f / cc);
    }
    uint2 val;
    val.x = (unsigned)bfbits(v[0]) | ((unsigned)bfbits(v[1]) << 16);
    val.y = (unsigned)bfbits(v[2]) | ((unsigned)bfbits(v[3]) << 16);
    int off = (row * 1024 + c4 * 8) ^ ((row & 7) << 4);
    *reinterpret_cast<uint2*>(lds + off) = val;
  }
  __syncthreads();
  mlp2_tail(lds, b2a, b2b, W2aT, W2bT, out_obj, o0, On);
}

// ---------------- phase B (CSR mode): sum runs -> object MLP ----------------
__global__ __launch_bounds__(512, 4) void phaseB_csr(
    const __hip_bfloat16* __restrict__ gathered,  // [2T+pad][512] bf16
    const int* __restrict__ offs,                 // [O+1]
    const float* __restrict__ b2a,
    const float* __restrict__ b2b,
    const __hip_bfloat16* __restrict__ W2aT,
    const __hip_bfloat16* __restrict__ W2bT,
    float* __restrict__ out_obj,
    int On)
{
  __shared__ __align__(16) char lds[65536];
  const int tid  = threadIdx.x;
  const int lane = tid & 63;
  const int wave = tid >> 6;
  const int o0   = blockIdx.x * 64;

  for (int jj = 0; jj < 8; ++jj) {
    int row = wave * 8 + jj;
    int r   = o0 + row;
    float acc[8] = {0.f, 0.f, 0.f, 0.f, 0.f, 0.f, 0.f, 0.f};
    float inv = 0.f;
    if (r < On) {
      int st = offs[r], en = offs[r + 1];
      int run = en - st;
      const char* gp = (const char*)gathered + (size_t)st * 1024 + lane * 16;
      // batch-8: issue up to 8 independent row loads, drain with vmcnt(0), consume.
      for (int i = 0; i < run; i += 8) {
        int m = run - i;
        m = m > 8 ? 8 : m;
        uifrag w0 = {0,0,0,0}, w1 = {0,0,0,0}, w2 = {0,0,0,0}, w3 = {0,0,0,0};
        uifrag w4 = {0,0,0,0}, w5 = {0,0,0,0}, w6 = {0,0,0,0}, w7 = {0,0,0,0};
        const char* bp = gp + (size_t)i * 1024;
        GL1(w0, bp);
        if (m > 1) { GL1(w1, bp + 1024); }
        if (m > 2) { GL1(w2, bp + 2048); }
        if (m > 3) { GL1(w3, bp + 3072); }
        if (m > 4) { GL1(w4, bp + 4096); }
        if (m > 5) { GL1(w5, bp + 5120); }
        if (m > 6) { GL1(w6, bp + 6144); }
        if (m > 7) { GL1(w7, bp + 7168); }
        asm volatile("s_waitcnt vmcnt(0)"
                     : "+v"(w0), "+v"(w1), "+v"(w2), "+v"(w3),
                       "+v"(w4), "+v"(w5), "+v"(w6), "+v"(w7) :: "memory");
        {
          bfrag bv = __builtin_bit_cast(bfrag, w0);
          #pragma unroll
          for (int q = 0; q < 8; ++q) acc[q] += b2f(bv[q]);
        }
        if (m > 1) {
          bfrag bv = __builtin_bit_cast(bfrag, w1);
          #pragma unroll
          for (int q = 0; q < 8; ++q) acc[q] += b2f(bv[q]);
        }
        if (m > 2) {
          bfrag bv = __builtin_bit_cast(bfrag, w2);
          #pragma unroll
          for (int q = 0; q < 8; ++q) acc[q] += b2f(bv[q]);
        }
        if (m > 3) {
          bfrag bv = __builtin_bit_cast(bfrag, w3);
          #pragma unroll
          for (int q = 0; q < 8; ++q) acc[q] += b2f(bv[q]);
        }
        if (m > 4) {
          bfrag bv = __builtin_bit_cast(bfrag, w4);
          #pragma unroll
          for (int q = 0; q < 8; ++q) acc[q] += b2f(bv[q]);
        }
        if (m > 5) {
          bfrag bv = __builtin_bit_cast(bfrag, w5);
          #pragma unroll
          for (int q = 0; q < 8; ++q) acc[q] += b2f(bv[q]);
        }
        if (m > 6) {
          bfrag bv = __builtin_bit_cast(bfrag, w6);
          #pragma unroll
          for (int q = 0; q < 8; ++q) acc[q] += b2f(bv[q]);
        }
        if (m > 7) {
          bfrag bv = __builtin_bit_cast(bfrag, w7);
          #pragma unroll
          for (int q = 0; q < 8; ++q) acc[q] += b2f(bv[q]);
        }
      }
      int cc = run;
      cc = cc < 1 ? 1 : cc;
      cc = cc > On ? On : cc;
      inv = 1.f / (float)cc;
    }
    unsigned short t[8];
    #pragma unroll
    for (int q = 0; q < 8; ++q) t[q] = bfbits(acc[q] * inv);
    uifrag val;
    val.x = (unsigned)t[0] | ((unsigned)t[1] << 16);
    val.y = (unsigned)t[2] | ((unsigned)t[3] << 16);
    val.z = (unsigned)t[4] | ((unsigned)t[5] << 16);
    val.w = (unsigned)t[6] | ((unsigned)t[7] << 16);
    int off = (row * 1024 + lane * 16) ^ ((row & 7) << 4);
    *reinterpret_cast<uifrag*>(lds + off) = val;
  }
  __syncthreads();
  mlp2_tail(lds, b2a, b2b, W2aT, W2bT, out_obj, o0, On);
}

extern "C" void kernel_launch(void* const* d_in, const int* in_sizes, int n_in,
                              void* d_out, int out_size, void* d_ws, size_t ws_size,
                              hipStream_t stream) {
  const float* obj   = (const float*)d_in[0];
  const float* pred  = (const float*)d_in[1];
  const int*   edges = (const int*)d_in[2];
  const float* W1a   = (const float*)d_in[3];
  const float* b1a   = (const float*)d_in[4];
  const float* W1b   = (const float*)d_in[5];
  const float* b1b   = (const float*)d_in[6];
  const float* W2a   = (const float*)d_in[7];
  const float* b2a   = (const float*)d_in[8];
  const float* W2b   = (const float*)d_in[9];
  const float* b2b   = (const float*)d_in[10];

  const int On = in_sizes[0] / DIN;   // 50000
  const int Tn = in_sizes[1] / DIN;   // 200000

  char* ws = (char*)d_ws;

  __hip_bfloat16* W1aP = (__hip_bfloat16*)ws;                   // packed [384*512]
  __hip_bfloat16* W1bP = W1aP + (size_t)HDIM * K1;              // packed [512*1152]
  __hip_bfloat16* W2aT = W1bP + (size_t)N2 * HDIM;              // [512][512]
  __hip_bfloat16* W2bT = W2aT + (size_t)HDIM * HDIM;            // [128][512]
  size_t wend = ((((size_t)(HDIM * K1 + N2 * HDIM + HDIM * HDIM + HDIM * DOUT)) * 2) + 255) & ~(size_t)255;

  // CSR layout
  int*   cnt    = (int*)(ws + wend);
  int*   offs   = cnt + On;              // [On+1]
  int*   cur    = offs + (On + 1);
  int*   slot_s = cur + On;
  int*   slot_o = slot_s + Tn;
  int*   bsum   = slot_o + Tn;           // [64]
  int*   bbase  = bsum + 64;             // [64]
  size_t gath_off = (wend + ((size_t)(3 * On + 1 + 2 * Tn + 128)) * 4 + 255) & ~(size_t)255;
  __hip_bfloat16* gathered = (__hip_bfloat16*)(ws + gath_off);
  size_t need_csr = gath_off + (size_t)(2 * Tn + 64) * HDIM * 2;  // +dump rows

  // atomic layout (fallback)
  float* pooled  = (float*)(ws + wend);
  float* countsf = pooled + (size_t)On * HDIM;

  bool use_csr = (ws_size >= need_csr);

  {
    int n;
    n = K1 * HDIM;   kpack<<<(n + 255) / 256, 256, 0, stream>>>(W1a, W1aP, K1, HDIM);
    n = HDIM * N2;   kpack<<<(n + 255) / 256, 256, 0, stream>>>(W1b, W1bP, HDIM, N2);
    n = HDIM * HDIM; ktranspose<<<(n + 255) / 256, 256, 0, stream>>>(W2a, W2aT, HDIM, HDIM);
    n = HDIM * DOUT; ktranspose<<<(n + 255) / 256, 256, 0, stream>>>(W2b, W2bT, HDIM, DOUT);
  }

  float* out_obj = (float*)d_out;
  float* out_p   = out_obj + (size_t)On * DOUT;

  const int gridA = (Tn + MB - 1) / MB;
  const int nb    = (On + 1023) >> 10;   // scan blocks (<= 64 for On <= 65536)

  if (use_csr) {
    (void)hipMemsetAsync(cnt, 0, (size_t)On * 4, stream);
    khist <<<(Tn + 255) / 256, 256, 0, stream>>>(edges, cnt, Tn);
    kscan1<<<nb, 1024, 0, stream>>>(cnt, offs, bsum, On);
    kscan2<<<1, 1024, 0, stream>>>(bsum, bbase, nb, offs, On);
    kscan3<<<(On + 255) / 256, 256, 0, stream>>>(offs, bbase, cur, On);
    kslot <<<(Tn + 255) / 256, 256, 0, stream>>>(edges, cur, slot_s, slot_o, Tn);
    phaseA<true><<<gridA, 512, 0, stream>>>(obj, pred, edges, b1a, b1b, W1aP, W1bP,
                                            nullptr, nullptr, slot_s, slot_o, gathered,
                                            out_p, Tn);
    phaseB_csr<<<(On + 63) / 64, 512, 0, stream>>>(gathered, offs, b2a, b2b, W2aT, W2bT,
                                                   out_obj, On);
  } else {
    (void)hipMemsetAsync(pooled, 0, (size_t)On * HDIM * 4 + (size_t)On * 4, stream);
    phaseA<false><<<gridA, 512, 0, stream>>>(obj, pred, edges, b1a, b1b, W1aP, W1bP,
                                             pooled, countsf, nullptr, nullptr, nullptr,
                                             out_p, Tn);
    phaseB_atomic<<<(On + 63) / 64, 512, 0, stream>>>(pooled, countsf, b2a, b2b, W2aT, W2bT,
                                                      out_obj, On);
  }
}